// Round 6
// baseline (677.358 us; speedup 1.0000x reference)
//
#include <hip/hip_runtime.h>

#define U 128
#define BATCH 2048
#define NL 8
#define NS 8                       /* NS=15 vs 10 bit-identical -> contraction <=0.36; NS=8 residual <1e-3 */
#define DTc 0.1f
#define TENf 10.0f                 /* DT/EPS */
#define INVC (1.0f/11.0f)          /* 1/(1+DT/EPS) */
#define AFACT (0.01f/11.0f)        /* DT^2 / c */
#define AST 264                    /* A-tile LDS stride (u16); 132 dwords -> b128 reads conflict-free */

typedef unsigned short u16;
typedef unsigned int u32;
typedef __attribute__((ext_vector_type(8))) short bf16x8;
typedef __attribute__((ext_vector_type(4))) float f32x4;
#define MFMA16(a,b,c) __builtin_amdgcn_mfma_f32_16x16x32_bf16(a,b,c,0,0,0)

__device__ __forceinline__ float bf2f(u16 h){ return __uint_as_float(((u32)h)<<16); }
__device__ __forceinline__ u16 f2bf(float f){
  u32 u = __float_as_uint(f);
  u += 0x7FFFu + ((u >> 16) & 1u);
  return (u16)(u >> 16);
}
__device__ __forceinline__ float fast_tanh(float x){
  float e = __expf(2.0f*x);
  return 1.0f - __fdividef(2.0f, e + 1.0f);
}
__device__ __forceinline__ int detect_md(const u16* x, int* s_bad, int t, int nthr){
  if(t==0) *s_bad = 0;
  __syncthreads();
  int f=0;
  for(int i=t;i<4096;i+=nthr){ float v = bf2f(x[i]); if(!(fabsf(v)<16.0f)) f=1; }
  if(f) atomicOr(s_bad,1);
  __syncthreads();
  return *s_bad ? 0 : 1;   // 1 = bf16 inputs
}
__device__ __forceinline__ bf16x8 ld8f(const float* p){
  float4 f0 = *(const float4*)p, f1 = *(const float4*)(p+4);
  bf16x8 v;
  v[0]=(short)f2bf(f0.x); v[1]=(short)f2bf(f0.y); v[2]=(short)f2bf(f0.z); v[3]=(short)f2bf(f0.w);
  v[4]=(short)f2bf(f1.x); v[5]=(short)f2bf(f1.y); v[6]=(short)f2bf(f1.z); v[7]=(short)f2bf(f1.w);
  return v;
}
// LDS-only barrier (does not drain vmcnt).
__device__ __forceinline__ void lgkm_barrier(){
  __builtin_amdgcn_sched_barrier(0);
  asm volatile("s_waitcnt lgkmcnt(0)\n\ts_barrier" ::: "memory");
  __builtin_amdgcn_sched_barrier(0);
}
// Exchange-data atomics: agent-scope relaxed -> data lives at the device
// coherence point (no dirty per-XCD L2, no wbl2 fences — R5 lesson).
__device__ __forceinline__ void ast32(u32* p, u32 v){
  __hip_atomic_store(p, v, __ATOMIC_RELAXED, __HIP_MEMORY_SCOPE_AGENT);
}
__device__ __forceinline__ u32 ald32(const u32* p){
  return __hip_atomic_load(p, __ATOMIC_RELAXED, __HIP_MEMORY_SCOPE_AGENT);
}

// ---------------- s1: convert W + transpose, 128 blocks ----------------------
__global__ __launch_bounds__(256) void convK(
    const void* __restrict__ xraw, const void* __restrict__ wb,
    u16* __restrict__ Wg, u16* __restrict__ Wtg){
  __shared__ int s_bad;
  const int t = threadIdx.x;
  const int md = detect_md((const u16*)xraw, &s_bad, t, 256);
  const int g = blockIdx.x*256 + t, GS = gridDim.x*256;
  for(int i=g;i<131072;i+=GS){
    u16 h = md ? ((const u16*)wb)[i] : f2bf(((const float*)wb)[i]);
    Wg[i] = h;
    int L = i>>14, j = i & 16383;
    Wtg[(L<<14) + (j&127)*U + (j>>7)] = h;
  }
}

// block tile: 16 rows x 128 cols, K=128; A[m][k] (lda), B[n][k] (ldb). 256 thr.
template<typename EPI>
__device__ __forceinline__ void tile16(const u16* __restrict__ A, int lda,
                                       const u16* __restrict__ B, int ldb, EPI epi){
  const int lane = threadIdx.x & 63, w = threadIdx.x >> 6;
  const int ln = lane & 15, lq = lane >> 4;
  const int n0 = 32*w + ln, n1 = n0 + 16;
  bf16x8 af[4], b0[4], b1[4];
  #pragma unroll
  for(int kt=0;kt<4;kt++){
    af[kt] = *(const bf16x8*)&A[ln*lda + kt*32 + lq*8];
    b0[kt] = *(const bf16x8*)&B[n0*ldb + kt*32 + lq*8];
    b1[kt] = *(const bf16x8*)&B[n1*ldb + kt*32 + lq*8];
  }
  f32x4 a0 = {0,0,0,0}, a1 = {0,0,0,0};
  #pragma unroll
  for(int kt=0;kt<4;kt++){ a0 = MFMA16(af[kt], b0[kt], a0); a1 = MFMA16(af[kt], b1[kt], a1); }
  epi(a0, a1, n0, n1);
}

// ---------------- s2: P = AFACT * Wt @ Wt ------------------------------------
__global__ __launch_bounds__(256) void gemmP(const u16* __restrict__ Wtg, u16* __restrict__ Pg){
  const int L = blockIdx.x >> 3, mt = blockIdx.x & 7;
  const int lq = (threadIdx.x & 63) >> 4;
  const u16* WtL = Wtg + (L<<14);
  tile16(WtL + mt*16*U, U, WtL, U, [&](f32x4 a0, f32x4 a1, int n0, int n1){
    #pragma unroll
    for(int r=0;r<4;r++){
      int row = mt*16 + lq*4 + r;
      Pg[(L<<14) + row*U + n0] = f2bf(AFACT*a0[r]);
      Pg[(L<<14) + row*U + n1] = f2bf(AFACT*a1[r]);
    }
  });
}
// ---------------- s3: S = INVC(I - P + P@P) -> Fb00 --------------------------
__global__ __launch_bounds__(256) void gemmS(const u16* __restrict__ Pg, u16* __restrict__ Fb){
  const int L = blockIdx.x >> 3, mt = blockIdx.x & 7;
  const int lq = (threadIdx.x & 63) >> 4;
  const u16* PL = Pg + (L<<14);
  u16* FbL = Fb + (size_t)L*65536;
  tile16(PL + mt*16*U, U, PL, U, [&](f32x4 a0, f32x4 a1, int n0, int n1){
    #pragma unroll
    for(int r=0;r<4;r++){
      int row = mt*16 + lq*4 + r;
      FbL[row*256 + n0] = f2bf(INVC*(((row==n0)?1.0f:0.0f) - bf2f(PL[row*U+n0]) + a0[r]));
      FbL[row*256 + n1] = f2bf(INVC*(((row==n1)?1.0f:0.0f) - bf2f(PL[row*U+n1]) + a1[r]));
    }
  });
}
// ---------------- s4: Q = DT * S @ Wt -> Fb01, Fb10^T ------------------------
__global__ __launch_bounds__(256) void gemmQ(const u16* __restrict__ Fb, const u16* __restrict__ Wg,
                                             u16* __restrict__ FbW){
  const int L = blockIdx.x >> 3, mt = blockIdx.x & 7;
  const int lq = (threadIdx.x & 63) >> 4;
  const u16* FbL = Fb + (size_t)L*65536;
  u16* FbO = FbW + (size_t)L*65536;
  tile16(FbL + mt*16*256, 256, Wg + (L<<14), U, [&](f32x4 a0, f32x4 a1, int n0, int n1){
    #pragma unroll
    for(int r=0;r<4;r++){
      int row = mt*16 + lq*4 + r;
      u16 q0 = f2bf(DTc*a0[r]), q1 = f2bf(DTc*a1[r]);
      FbO[row*256 + 128 + n0] = q0;
      FbO[row*256 + 128 + n1] = q1;
      FbO[(128+n0)*256 + row] = q0;
      FbO[(128+n1)*256 + row] = q1;
    }
  });
}
// ---------------- s5: R = DT * W @ Q -> Fb11 ---------------------------------
__global__ __launch_bounds__(256) void gemmR(const u16* __restrict__ Wg, u16* __restrict__ Fb){
  const int L = blockIdx.x >> 3, mt = blockIdx.x & 7;
  const int lq = (threadIdx.x & 63) >> 4;
  u16* FbL = Fb + (size_t)L*65536;
  tile16(Wg + (L<<14) + mt*16*U, U, FbL + 128*256, 256, [&](f32x4 a0, f32x4 a1, int n0, int n1){
    #pragma unroll
    for(int r=0;r<4;r++){
      int row = mt*16 + lq*4 + r;
      FbL[(128+row)*256 + 128 + n0] = f2bf(DTc*a0[r]);
      FbL[(128+row)*256 + 128 + n1] = f2bf(DTc*a1[r]);
    }
  });
}
// ---------------- s6: swizzle F to fragment-major ----------------------------
__global__ __launch_bounds__(256) void swizK(const u16* __restrict__ Fb, u16* __restrict__ Fsw){
  const int L = blockIdx.x >> 3, part = blockIdx.x & 7;
  const u16* FbL = Fb + (size_t)L*65536;
  for(int i = part*1024 + threadIdx.x; i < (part+1)*1024; i += 256){
    int lanei = i & 63, kt = (i>>6)&7, c = (i>>9)&3, w = (i>>11)&3;
    int lni = lanei & 15, lqi = lanei >> 4;
    int row_n = 64*w + 16*c + lni;
    int col_k = kt*32 + lqi*8;
    *(bf16x8*)&Fsw[((size_t)L*8192 + i)*8] = *(const bf16x8*)&FbL[row_n*256 + col_k];
  }
}

// ---------------- mainK2: pair-split, 256 blocks x 512 thr -------------------
// Pair p = (block p [role T, cols 0..127], block p+128 [role V, cols 128..255]),
// both on batch rows 16p..16p+15. Each streams HALF of F per step (64 KB/CU —
// the per-CU VMEM stream is the measured invariant wall). Full At rebuilt per
// step: own half local, partner half via agent-scope atomic slabs + per-pair
// monotonic flags (2-slot; mutual dependency gives distance-2 overwrite safety).
// All shipped f32 bit-exact -> output bit-identical to the proven kernel.
__global__ __launch_bounds__(512,2) void mainK2(
    const void* __restrict__ xraw, const void* __restrict__ w_in,
    const void* __restrict__ b_in, const void* __restrict__ bb,
    const bf16x8* __restrict__ Fsw, const void* __restrict__ w_out,
    const void* __restrict__ b_out, void* __restrict__ outraw,
    u32* __restrict__ slabYg, u32* __restrict__ slabTg, u32* __restrict__ flags){
  __shared__ u16 At[2][16*AST];          // ping-pong A tiles [T | r_u]
  __shared__ u16 zh16[NL][16][132];      // T-role only
  __shared__ float zinu[16*U];
  __shared__ float bbL[NL*U];
  __shared__ float lg[16*12];
  __shared__ int s_bad;
  float* uout = (float*)&At[0][0];

  const int t = threadIdx.x;
  const int lane = t & 63, wid = t >> 6, ln = lane & 15, lq = lane >> 4;
  const int pair = blockIdx.x & 127;
  const int role = blockIdx.x >> 7;     // 0 = T (cols 0..127), 1 = V (cols 128..255)
  const int r0 = pair * 16;
  const int n  = 16*wid + ln;           // T-col (role 0) / uc (role 1)
  const int uc = n;

  u32* slabY = slabYg + pair*4096;      // [slot][row*128+uc] f32-bits
  u32* slabT = slabTg + pair*2048;      // [slot][n*8 + q] packed u16 row-pairs
  u32* myflag    = flags + pair*32 + (role ? 16 : 0);
  u32* otherflag = flags + pair*32 + (role ? 0 : 16);

  const int md = detect_md((const u16*)xraw, &s_bad, t, 512);
  for(int i=t;i<NL*U;i+=512)
    bbL[i] = DTc * (md ? bf2f(((const u16*)bb)[i]) : ((const float*)bb)[i]);
  __syncthreads();

  // ---- phase 1: z1 = x @ w_in^T + b_in (both roles, deterministic -> identical bits) ----
  {
    const u16*   wrb = (const u16*)w_in   + (size_t)n*784;
    const float* wrf = (const float*)w_in + (size_t)n*784;
    const u16*   xrb = (const u16*)xraw   + (size_t)(r0+ln)*784;
    const float* xrf = (const float*)xraw + (size_t)(r0+ln)*784;
    f32x4 acc = {0,0,0,0};
    const bf16x8 z8 = {0,0,0,0,0,0,0,0};
    if(md){
      #pragma unroll
      for(int kt=0; kt<24; ++kt){
        int k0 = kt*32 + lq*8;
        acc = MFMA16(*(const bf16x8*)(xrb + k0), *(const bf16x8*)(wrb + k0), acc);
      }
      { int k0 = 768 + lq*8;
        bf16x8 av = z8, bv = z8;
        if(lq < 2){ av = *(const bf16x8*)(xrb + k0); bv = *(const bf16x8*)(wrb + k0); }
        acc = MFMA16(av, bv, acc);
      }
    } else {
      #pragma unroll 4
      for(int kt=0; kt<24; ++kt){
        int k0 = kt*32 + lq*8;
        acc = MFMA16(ld8f(xrf + k0), ld8f(wrf + k0), acc);
      }
      { int k0 = 768 + lq*8;
        bf16x8 av = z8, bv = z8;
        if(lq < 2){ av = ld8f(xrf + k0); bv = ld8f(wrf + k0); }
        acc = MFMA16(av, bv, acc);
      }
    }
    float bi = md ? bf2f(((const u16*)b_in)[n]) : ((const float*)b_in)[n];
    #pragma unroll
    for(int r=0;r<4;r++) zinu[(lq*4+r)*U + n] = acc[r] + bi;
  }
  __syncthreads();

  // ---- init: zh (T only), full At(0) (both), ru regs (V only) ----
  if(role==0){
    for(int i=t; i<NL*16*128; i+=512){
      int l = i>>11, row = (i>>7)&15, c = i & 127;
      zh16[l][row][c] = f2bf(zinu[row*U + c]);
    }
  }
  float ru[4];
  #pragma unroll
  for(int r=0;r<4;r++){
    int row = lq*4 + r;
    At[0][row*AST + n] = f2bf((TENf + 1.0f) * fast_tanh(zinu[row*U + n]));
    float v = zinu[row*U + uc] + bbL[uc];
    ru[r] = v;
    At[0][row*AST + 128 + uc] = f2bf(v);
  }
  // F fragment base: role 0 -> rows 0..127 (w 0,1); role 1 -> rows 128..255 (w 2,3)
  const bf16x8* fbase = Fsw + (2*role + (wid>>2))*2048 + (wid&3)*512 + lane;
  bf16x8 BfA[8], BfB[8];
  #pragma unroll
  for(int kt=0;kt<8;kt++) BfA[kt] = fbase[kt*64];
  __syncthreads();

#define STEPBODY(STEPV, BC, BN, CURC) { \
    const int l = (STEPV) & 7; \
    const int lnext = (l+1) & 7; \
    const bool last = ((STEPV) == NS*NL-1); \
    const int slot = (STEPV) & 1; \
    { const bf16x8* fp = fbase + lnext*8192; \
      _Pragma("unroll") \
      for(int kt=0;kt<8;kt++) BN[kt] = fp[kt*64]; } \
    bf16x8 at8[8]; \
    _Pragma("unroll") \
    for(int kt=0;kt<8;kt++) at8[kt] = *(const bf16x8*)&At[CURC][ln*AST + kt*32 + lq*8]; \
    float th[4]; \
    if(role==0 && !last){ \
      _Pragma("unroll") \
      for(int r=0;r<4;r++) th[r] = TENf * fast_tanh(bf2f(zh16[lnext][lq*4 + r][n])); \
    } \
    f32x4 acc = {0,0,0,0}; \
    _Pragma("unroll") \
    for(int kt=0;kt<8;kt++) acc = MFMA16(at8[kt], BC[kt], acc); \
    if(role==0){ \
      if(!last){ \
        const bool wrap = (l == 7); \
        u32* sT = slabT + slot*1024; \
        u16 tt[4]; \
        _Pragma("unroll") \
        for(int r=0;r<4;r++){ \
          int row = lq*4 + r; \
          float base = wrap ? fast_tanh(zinu[row*U + n]) : acc[r]; \
          tt[r] = f2bf(th[r] + base); \
          At[1-(CURC)][row*AST + n] = tt[r]; \
        } \
        ast32(&sT[n*8 + lq*2 + 0], (u32)tt[0] | ((u32)tt[1]<<16)); \
        ast32(&sT[n*8 + lq*2 + 1], (u32)tt[2] | ((u32)tt[3]<<16)); \
      } \
    } else { \
      if(last){ \
        _Pragma("unroll") \
        for(int r=0;r<4;r++){ \
          int row = lq*4 + r; \
          uout[row*U + uc] = zinu[row*U + uc] + bbL[7*U + uc] - acc[r]; \
        } \
      } else { \
        const bool wrap = (l == 7); \
        u32* sY = slabY + slot*2048; \
        _Pragma("unroll") \
        for(int r=0;r<4;r++){ \
          int row = lq*4 + r; \
          float yu = ru[r] - acc[r]; \
          ast32(&sY[(row<<7) + uc], __float_as_uint(yu)); \
          float rn = wrap ? (zinu[row*U + uc] + bbL[uc]) : (yu + bbL[(l+1)*U + uc]); \
          ru[r] = rn; \
          At[1-(CURC)][row*AST + 128 + uc] = f2bf(rn); \
        } \
      } \
    } \
    if(!last){ \
      __syncthreads();  /* drains vmcnt: all slab atomic stores complete */ \
      if(t==0){ \
        __hip_atomic_store(myflag, (u32)((STEPV)+1), __ATOMIC_RELEASE, __HIP_MEMORY_SCOPE_AGENT); \
        while(__hip_atomic_load(otherflag, __ATOMIC_ACQUIRE, __HIP_MEMORY_SCOPE_AGENT) < (u32)((STEPV)+1)) \
          __builtin_amdgcn_s_sleep(1); \
      } \
      __syncthreads(); \
      if(role==0){ \
        const u32* sY = slabY + slot*2048; \
        const bool wrap = (l == 7); \
        _Pragma("unroll") \
        for(int j=0;j<4;j++){ \
          int idx = t*4 + j, row = idx>>7, ucc = idx & 127; \
          float yu = __uint_as_float(ald32(&sY[idx])); \
          zh16[l][row][ucc] = f2bf(yu); \
          float rn = wrap ? (zinu[row*U + ucc] + bbL[ucc]) : (yu + bbL[(l+1)*U + ucc]); \
          At[1-(CURC)][row*AST + 128 + ucc] = f2bf(rn); \
        } \
      } else { \
        const u32* sT = slabT + slot*1024; \
        _Pragma("unroll") \
        for(int j=0;j<2;j++){ \
          int w = t*2 + j, nn = w>>3, q = w & 7; \
          u32 v = ald32(&sT[w]); \
          At[1-(CURC)][(2*q)*AST + nn]   = (u16)(v & 0xffffu); \
          At[1-(CURC)][(2*q+1)*AST + nn] = (u16)(v >> 16); \
        } \
      } \
      lgkm_barrier(); \
    } \
  }

  for(int sp=0; sp<NS*NL; sp+=2){
    STEPBODY(sp,   BfA, BfB, 0)
    STEPBODY(sp+1, BfB, BfA, 1)
  }
#undef STEPBODY

  // ---- logits + softmax: V-role only (has uout) ----
  if(role==1){
    __syncthreads();
    if(t < 160){
      int mm = t/10, o = t - mm*10;
      float a = md ? bf2f(((const u16*)b_out)[o]) : ((const float*)b_out)[o];
      if(md){
        const u16* wo = (const u16*)w_out + o*U;
        for(int k=0;k<U;k++) a += uout[mm*U + k]*bf2f(wo[k]);
      } else {
        const float* wo = (const float*)w_out + o*U;
        for(int k=0;k<U;k++) a += uout[mm*U + k]*wo[k];
      }
      lg[mm*12 + o] = a;
    }
    __syncthreads();
    if(t < 16){
      float mx = -1e30f;
      for(int o=0;o<10;o++) mx = fmaxf(mx, lg[t*12 + o]);
      float e[10]; float sum = 0.0f;
      for(int o=0;o<10;o++){ e[o] = __expf(lg[t*12 + o] - mx); sum += e[o]; }
      float inv = 1.0f / sum;
      for(int o=0;o<10;o++){
        float pv = e[o]*inv;
        if(md) ((u16*)outraw)[(size_t)(r0 + t)*10 + o] = f2bf(pv);
        else   ((float*)outraw)[(size_t)(r0 + t)*10 + o] = pv;
      }
    }
  }
}

extern "C" void kernel_launch(void* const* d_in, const int* in_sizes, int n_in,
                              void* d_out, int out_size, void* d_ws, size_t ws_size,
                              hipStream_t stream) {
  char* p = (char*)d_ws;
  u16* Fb      = (u16*)p;  p += (size_t)8*256*256*2;   // 1 MB
  u16* Fsw     = (u16*)p;  p += (size_t)8*256*256*2;   // 1 MB
  u16* Wg      = (u16*)p;  p += (size_t)8*128*128*2;   // 256 KB
  u16* Wtg     = (u16*)p;  p += (size_t)8*128*128*2;
  u16* Pg      = (u16*)p;  p += (size_t)8*128*128*2;
  u32* slabY   = (u32*)p;  p += (size_t)128*2*2048*4;  // 2 MB
  u32* slabT   = (u32*)p;  p += (size_t)128*2*1024*4;  // 1 MB
  u32* flags   = (u32*)p;  p += (size_t)128*32*4;      // 16 KB

  hipMemsetAsync(flags, 0, (size_t)128*32*4, stream);
  convK<<<128, 256, 0, stream>>>(d_in[0], d_in[3], Wg, Wtg);
  gemmP<<<64, 256, 0, stream>>>(Wtg, Pg);
  gemmS<<<64, 256, 0, stream>>>(Pg, Fb);
  gemmQ<<<64, 256, 0, stream>>>(Fb, Wg, Fb);
  gemmR<<<64, 256, 0, stream>>>(Wg, Fb);
  swizK<<<64, 256, 0, stream>>>(Fb, Fsw);
  mainK2<<<256, 512, 0, stream>>>(d_in[0], d_in[1], d_in[2], d_in[4],
                                  (const bf16x8*)Fsw, d_in[5], d_in[6], d_out,
                                  slabY, slabT, flags);
}

// Round 7
// 218.506 us; speedup vs baseline: 3.0999x; 3.0999x over previous
//
#include <hip/hip_runtime.h>

#define U 128
#define BATCH 2048
#define NL 8
#define NS 8                       /* NS=15 vs 10 bit-identical -> contraction <=0.36; NS=8 residual <1e-3 */
#define DTc 0.1f
#define TENf 10.0f                 /* DT/EPS */
#define INVC (1.0f/11.0f)          /* 1/(1+DT/EPS) */
#define AFACT (0.01f/11.0f)        /* DT^2 / c */
#define AST 264                    /* A-tile LDS stride (u16); 132 dwords -> b128 reads conflict-free */

typedef unsigned short u16;
typedef unsigned int u32;
typedef __attribute__((ext_vector_type(8))) short bf16x8;
typedef __attribute__((ext_vector_type(4))) float f32x4;
#define MFMA16(a,b,c) __builtin_amdgcn_mfma_f32_16x16x32_bf16(a,b,c,0,0,0)

__device__ __forceinline__ float bf2f(u16 h){ return __uint_as_float(((u32)h)<<16); }
__device__ __forceinline__ u16 f2bf(float f){
  u32 u = __float_as_uint(f);
  u += 0x7FFFu + ((u >> 16) & 1u);
  return (u16)(u >> 16);
}
__device__ __forceinline__ float fast_tanh(float x){
  float e = __expf(2.0f*x);
  return 1.0f - __fdividef(2.0f, e + 1.0f);
}
__device__ __forceinline__ int detect_md(const u16* x, int* s_bad, int t, int nthr){
  if(t==0) *s_bad = 0;
  __syncthreads();
  int f=0;
  for(int i=t;i<4096;i+=nthr){ float v = bf2f(x[i]); if(!(fabsf(v)<16.0f)) f=1; }
  if(f) atomicOr(s_bad,1);
  __syncthreads();
  return *s_bad ? 0 : 1;   // 1 = bf16 inputs
}
__device__ __forceinline__ bf16x8 ld8f(const float* p){
  float4 f0 = *(const float4*)p, f1 = *(const float4*)(p+4);
  bf16x8 v;
  v[0]=(short)f2bf(f0.x); v[1]=(short)f2bf(f0.y); v[2]=(short)f2bf(f0.z); v[3]=(short)f2bf(f0.w);
  v[4]=(short)f2bf(f1.x); v[5]=(short)f2bf(f1.y); v[6]=(short)f2bf(f1.z); v[7]=(short)f2bf(f1.w);
  return v;
}
// LDS-only barrier (does not drain vmcnt).
__device__ __forceinline__ void lgkm_barrier(){
  __builtin_amdgcn_sched_barrier(0);
  asm volatile("s_waitcnt lgkmcnt(0)\n\ts_barrier" ::: "memory");
  __builtin_amdgcn_sched_barrier(0);
}

// ---------------- prepB: one kernel, 64 independent blocks -------------------
// Block (L, mt): computes P, S, Q FULLY (redundant 8x, in-LDS — free since
// blocks are parallel on an idle machine), own R-slice, writes its share of
// Fsw. ZERO cross-block sync (reads only the coherent kernel input wb).
// Every accumulation chain = (row,col) with kt ascending + same f2bf points
// as the proven 6-kernel chain -> Fsw bit-identical.
// full 128x128x128: wave w owns col-group n0=16w+ln; B-frags hoisted (const
// across row-tiles); per (row,n) chain = kt ascending.
template<typename GB, typename EPI>
__device__ __forceinline__ void gfull(const u16* __restrict__ A, GB getB, EPI epi,
                                      int w, int ln, int lq){
  const int n0 = 16*w + ln;
  bf16x8 bfr[4];
  #pragma unroll
  for(int kt=0;kt<4;kt++) bfr[kt] = getB(n0, kt*32 + lq*8);
  #pragma unroll 2
  for(int rt=0; rt<8; rt++){
    f32x4 acc = {0,0,0,0};
    #pragma unroll
    for(int kt=0;kt<4;kt++){
      bf16x8 af = *(const bf16x8*)&A[(rt*16+ln)*U + kt*32 + lq*8];
      acc = MFMA16(af, bfr[kt], acc);
    }
    epi(acc, rt*16 + lq*4, n0);
  }
}

__global__ __launch_bounds__(512) void prepB(
    const void* __restrict__ xraw, const void* __restrict__ wb,
    u16* __restrict__ Fsw){
  __shared__ u16 bufA[16384];   // Wt -> S -> Qt
  __shared__ u16 bufB[16384];   // P  -> Q
  const int t = threadIdx.x;
  const int lane = t & 63, w = t >> 6, ln = lane & 15, lq = lane >> 4;
  const int L = blockIdx.x >> 3, mt = blockIdx.x & 7;
  const int md = detect_md((const u16*)xraw, (int*)bufA, t, 512);
  __syncthreads();   // s_bad overlays bufA: all lanes read it before Wt-conv writes
  const u16*   wbb = (const u16*)wb   + ((size_t)L<<14);
  const float* wbf = (const float*)wb + ((size_t)L<<14);

  // Wt (= f2bf(W) transposed) -> bufA
  for(int j=t;j<16384;j+=512){
    u16 h = md ? wbb[j] : f2bf(wbf[j]);
    bufA[(j&127)*U + (j>>7)] = h;
  }
  __syncthreads();

  auto gA = [&](int n,int k0)->bf16x8{ return *(const bf16x8*)&bufA[n*U+k0]; };
  auto gB = [&](int n,int k0)->bf16x8{ return *(const bf16x8*)&bufB[n*U+k0]; };
  auto gW = [&](int n,int k0)->bf16x8{
    if(md) return *(const bf16x8*)&wbb[n*U+k0];
    return ld8f(wbf + n*U + k0);
  };

  // P = AFACT * Wt @ Wt^T  -> bufB (full)
  gfull(bufA, gA, [&](f32x4 acc, int rowb, int n0){
    #pragma unroll
    for(int r=0;r<4;r++) bufB[(rowb+r)*U + n0] = f2bf(AFACT*acc[r]);
  }, w, ln, lq);
  __syncthreads();
  // S = INVC*(I - P + P@P)  -> bufA (full; Wt dead)
  gfull(bufB, gB, [&](f32x4 acc, int rowb, int n0){
    #pragma unroll
    for(int r=0;r<4;r++){
      int row = rowb + r;
      bufA[row*U + n0] = f2bf(INVC*(((row==n0)?1.0f:0.0f) - bf2f(bufB[row*U+n0]) + acc[r]));
    }
  }, w, ln, lq);
  __syncthreads();
  // Q = DT * S @ W^T  -> bufB (full; P dead). B from raw global W (== Wg bits).
  gfull(bufA, gW, [&](f32x4 acc, int rowb, int n0){
    #pragma unroll
    for(int r=0;r<4;r++) bufB[(rowb+r)*U + n0] = f2bf(DTc*acc[r]);
  }, w, ln, lq);
  __syncthreads();

  // swiz pass 1: this block's frag slice, quadrants F00 (S=bufA) / F01 (Q=bufB)
  for(int i = mt*1024 + t; i < (mt+1)*1024; i += 512){
    int wf = (i>>11)&3;
    if(wf >= 2) continue;
    int lanei = i & 63, kt = (i>>6)&7, c = (i>>9)&3;
    int row_n = 64*wf + 16*c + (lanei & 15);
    int col_k = kt*32 + (lanei >> 4)*8;
    bf16x8 v = (kt < 4) ? *(const bf16x8*)&bufA[row_n*U + col_k]
                        : *(const bf16x8*)&bufB[row_n*U + col_k - 128];
    *(bf16x8*)&Fsw[((size_t)L*8192 + i)*8] = v;
  }
  __syncthreads();
  // Qt = Q^T -> bufA (S dead: F00 swizzled, Q consumed it)
  for(int j=t;j<16384;j+=512) bufA[(j&127)*U + (j>>7)] = bufB[j];
  __syncthreads();
  // swiz pass 2: quadrant F10 (= Q^T = bufA)
  for(int i = mt*1024 + t; i < (mt+1)*1024; i += 512){
    int wf = (i>>11)&3, kt = (i>>6)&7;
    if(wf < 2 || kt >= 4) continue;
    int lanei = i & 63, c = (i>>9)&3;
    int row_n = 64*wf + 16*c + (lanei & 15);
    int col_k = kt*32 + (lanei >> 4)*8;
    *(bf16x8*)&Fsw[((size_t)L*8192 + i)*8] = *(const bf16x8*)&bufA[(row_n-128)*U + col_k];
  }
  // R-slice (rows mt*16..+16): A = raw W slice (global), B = Qt rows (bufA).
  // Epilogue scatters F11 elements straight to fragment-major Fsw.
  {
    const int n0 = 16*w + ln;
    bf16x8 bq[4];
    #pragma unroll
    for(int kt=0;kt<4;kt++) bq[kt] = *(const bf16x8*)&bufA[n0*U + kt*32 + lq*8];
    f32x4 acc = {0,0,0,0};
    #pragma unroll
    for(int kt=0;kt<4;kt++){
      bf16x8 af = gW(mt*16 + ln, kt*32 + lq*8);
      acc = MFMA16(af, bq[kt], acc);
    }
    const int wf = 2 + (mt>>2), cc = mt & 3;
    const int kt_ = 4 + (n0>>5), lqi = (n0>>3)&3, jj = n0 & 7;
    #pragma unroll
    for(int r=0;r<4;r++){
      int lni = lq*4 + r;
      int i = (wf<<11)|(cc<<9)|(kt_<<6)|(lqi<<4)|lni;
      Fsw[((size_t)L*8192 + i)*8 + jj] = f2bf(DTc*acc[r]);
    }
  }
}

// ---------------- main: 16 rows/block, 16 waves (4/SIMD), 1 barrier/step -----
// BYTE-IDENTICAL to R5's measured 125.6 us kernel.
__global__ __launch_bounds__(1024,4) void mainK(
    const void* __restrict__ xraw, const void* __restrict__ w_in,
    const void* __restrict__ b_in, const void* __restrict__ bb,
    const bf16x8* __restrict__ Fsw, const void* __restrict__ w_out,
    const void* __restrict__ b_out, void* __restrict__ outraw){
  __shared__ u16 At[2][16*AST];          // ping-pong A tiles [T | r_u]
  __shared__ u16 zh16[NL][16][132];      // stride 66 dwords -> u16 ops conflict-free
  __shared__ float zinu[16*U];
  __shared__ float bbL[NL*U];
  __shared__ float lg[16*12];
  __shared__ int s_bad;
  float* uout = (float*)&At[0][0];

  const int t = threadIdx.x;
  const int lane = t & 63, wid = t >> 6, ln = lane & 15, lq = lane >> 4;
  const int r0 = blockIdx.x * 16;

  const int md = detect_md((const u16*)xraw, &s_bad, t, 1024);
  for(int i=t;i<NL*U;i+=1024)
    bbL[i] = DTc * (md ? bf2f(((const u16*)bb)[i]) : ((const float*)bb)[i]);
  __syncthreads();

  // ---- phase 1: z1 = x @ w_in^T + b_in (waves 0..7 only; cols 0..127) ----
  if(wid < 8){
    const int n0 = 16*wid + ln;
    const u16*   wrb = (const u16*)w_in   + (size_t)n0*784;
    const float* wrf = (const float*)w_in + (size_t)n0*784;
    const u16*   xrb = (const u16*)xraw   + (size_t)(r0+ln)*784;
    const float* xrf = (const float*)xraw + (size_t)(r0+ln)*784;
    f32x4 acc = {0,0,0,0};
    const bf16x8 z8 = {0,0,0,0,0,0,0,0};
    if(md){
      #pragma unroll
      for(int kt=0; kt<24; ++kt){
        int k0 = kt*32 + lq*8;
        acc = MFMA16(*(const bf16x8*)(xrb + k0), *(const bf16x8*)(wrb + k0), acc);
      }
      { int k0 = 768 + lq*8;
        bf16x8 av = z8, bv = z8;
        if(lq < 2){ av = *(const bf16x8*)(xrb + k0); bv = *(const bf16x8*)(wrb + k0); }
        acc = MFMA16(av, bv, acc);
      }
    } else {
      #pragma unroll 4
      for(int kt=0; kt<24; ++kt){
        int k0 = kt*32 + lq*8;
        acc = MFMA16(ld8f(xrf + k0), ld8f(wrf + k0), acc);
      }
      { int k0 = 768 + lq*8;
        bf16x8 av = z8, bv = z8;
        if(lq < 2){ av = ld8f(xrf + k0); bv = ld8f(wrf + k0); }
        acc = MFMA16(av, bv, acc);
      }
    }
    float bi = md ? bf2f(((const u16*)b_in)[n0]) : ((const float*)b_in)[n0];
    #pragma unroll
    for(int r=0;r<4;r++) zinu[(lq*4+r)*U + n0] = acc[r] + bi;
  }
  __syncthreads();

  // ---- init: z-history (u16, unpacked), A-tile(0), r_u regs ----
  for(int i=t; i<NL*16*128; i+=1024){
    int l = i>>11, row = (i>>7)&15, c = i & 127;
    zh16[l][row][c] = f2bf(zinu[row*U + c]);
  }
  float ru[4];
  if(wid < 8){
    const int n = 16*wid + ln;
    #pragma unroll
    for(int r=0;r<4;r++){
      int row = lq*4 + r;
      At[0][row*AST + n] = f2bf((TENf + 1.0f) * fast_tanh(zinu[row*U + n]));
    }
  } else {
    const int uc = 16*(wid-8) + ln;
    #pragma unroll
    for(int r=0;r<4;r++){
      int row = lq*4 + r;
      float v = zinu[row*U + uc] + bbL[uc];
      ru[r] = v;
      At[0][row*AST + 128 + uc] = f2bf(v);
    }
  }
  // F fragment base for this wave (coalesced fragment-major)
  const bf16x8* fbase = Fsw + (wid>>2)*2048 + (wid&3)*512 + lane;
  bf16x8 BfA[8], BfB[8];
  #pragma unroll
  for(int kt=0;kt<8;kt++) BfA[kt] = fbase[kt*64];
  __syncthreads();

#define STEPBODY(STEPV, BC, BN, CURC) { \
    const int l = (STEPV) & 7; \
    const int lnext = (l+1) & 7; \
    const bool last = ((STEPV) == NS*NL-1); \
    { const bf16x8* fp = fbase + lnext*8192; \
      _Pragma("unroll") \
      for(int kt=0;kt<8;kt++) BN[kt] = fp[kt*64]; } \
    bf16x8 at8[8]; \
    _Pragma("unroll") \
    for(int kt=0;kt<8;kt++) at8[kt] = *(const bf16x8*)&At[CURC][ln*AST + kt*32 + lq*8]; \
    float th[4]; \
    if(wid < 8 && !last){ \
      _Pragma("unroll") \
      for(int r=0;r<4;r++) th[r] = TENf * fast_tanh(bf2f(zh16[lnext][lq*4 + r][16*wid + ln])); \
    } \
    f32x4 acc = {0,0,0,0}; \
    _Pragma("unroll") \
    for(int kt=0;kt<8;kt++) acc = MFMA16(at8[kt], BC[kt], acc); \
    if(wid < 8){ \
      if(!last){ \
        const bool wrap = (l == 7); \
        const int n = 16*wid + ln; \
        _Pragma("unroll") \
        for(int r=0;r<4;r++){ \
          int row = lq*4 + r; \
          float base = wrap ? fast_tanh(zinu[row*U + n]) : acc[r]; \
          At[1-(CURC)][row*AST + n] = f2bf(th[r] + base); \
        } \
      } \
    } else { \
      const int uc0 = 16*(wid-8) + ln; \
      _Pragma("unroll") \
      for(int r=0;r<4;r++){ \
        int row = lq*4 + r; \
        float yu = ru[r] - acc[r]; \
        zh16[l][row][uc0] = f2bf(yu); \
        if(last){ \
          uout[row*U + uc0] = zinu[row*U + uc0] + bbL[7*U + uc0] - acc[r]; \
        } else if(l == 7){ \
          float rn = zinu[row*U + uc0] + bbL[uc0]; \
          ru[r] = rn; \
          At[1-(CURC)][row*AST + 128 + uc0] = f2bf(rn); \
        } else { \
          float rn = yu + bbL[(l+1)*U + uc0]; \
          ru[r] = rn; \
          At[1-(CURC)][row*AST + 128 + uc0] = f2bf(rn); \
        } \
      } \
    } \
    lgkm_barrier(); \
  }

  for(int sp=0; sp<NS*NL; sp+=2){
    STEPBODY(sp,   BfA, BfB, 0)
    STEPBODY(sp+1, BfB, BfA, 1)
  }
#undef STEPBODY

  // ---- logits + softmax (w_out/b_out read directly, dual-mode) ----
  if(t < 160){
    int mm = t/10, o = t - mm*10;
    float a = md ? bf2f(((const u16*)b_out)[o]) : ((const float*)b_out)[o];
    if(md){
      const u16* wo = (const u16*)w_out + o*U;
      for(int k=0;k<U;k++) a += uout[mm*U + k]*bf2f(wo[k]);
    } else {
      const float* wo = (const float*)w_out + o*U;
      for(int k=0;k<U;k++) a += uout[mm*U + k]*wo[k];
    }
    lg[mm*12 + o] = a;
  }
  __syncthreads();
  if(t < 16){
    float mx = -1e30f;
    for(int o=0;o<10;o++) mx = fmaxf(mx, lg[t*12 + o]);
    float e[10]; float sum = 0.0f;
    for(int o=0;o<10;o++){ e[o] = __expf(lg[t*12 + o] - mx); sum += e[o]; }
    float inv = 1.0f / sum;
    for(int o=0;o<10;o++){
      float pv = e[o]*inv;
      if(md) ((u16*)outraw)[(size_t)(r0 + t)*10 + o] = f2bf(pv);
      else   ((float*)outraw)[(size_t)(r0 + t)*10 + o] = pv;
    }
  }
}

extern "C" void kernel_launch(void* const* d_in, const int* in_sizes, int n_in,
                              void* d_out, int out_size, void* d_ws, size_t ws_size,
                              hipStream_t stream) {
  u16* Fsw = (u16*)d_ws;   // 8 layers x 256x256 bf16 fragment-major = 1 MB

  prepB<<<64, 512, 0, stream>>>(d_in[0], d_in[3], Fsw);
  mainK<<<BATCH/16, 1024, 0, stream>>>(d_in[0], d_in[1], d_in[2], d_in[4],
                                       (const bf16x8*)Fsw, d_in[5], d_in[6], d_out);
}

// Round 9
// 201.991 us; speedup vs baseline: 3.3534x; 1.0818x over previous
//
#include <hip/hip_runtime.h>

#define U 128
#define BATCH 2048
#define NL 8
#define NS 8                       /* NS=15 vs 10 bit-identical -> contraction <=0.36; NS=8 residual <1e-3 */
#define DTc 0.1f
#define TENf 10.0f                 /* DT/EPS */
#define INVC (1.0f/11.0f)          /* 1/(1+DT/EPS) */
#define AFACT (0.01f/11.0f)        /* DT^2 / c */
#define AST 264                    /* A-tile LDS stride (u16); 132 dwords -> b128 reads conflict-free */

typedef unsigned short u16;
typedef unsigned int u32;
typedef __attribute__((ext_vector_type(8))) short bf16x8;
typedef __attribute__((ext_vector_type(4))) float f32x4;
#define MFMA16(a,b,c) __builtin_amdgcn_mfma_f32_16x16x32_bf16(a,b,c,0,0,0)

/* XOR-swizzled u16 index into a 128x128 LDS tile (T2 / Guideline 4):
   granule (16B) address = row*128 + ((c8 ^ (row&7))<<3). Bijective per row,
   keeps b128 contiguity, spreads ln-varying accesses across all 32 banks. */
#define SWZ8(row, c8)  (((row)<<7) + ((((c8) ^ ((row)&7)))<<3))
#define SWZE(row, col) (SWZ8(row, (col)>>3) + ((col)&7))

__device__ __forceinline__ float bf2f(u16 h){ return __uint_as_float(((u32)h)<<16); }
__device__ __forceinline__ u16 f2bf(float f){
  u32 u = __float_as_uint(f);
  u += 0x7FFFu + ((u >> 16) & 1u);
  return (u16)(u >> 16);
}
__device__ __forceinline__ float fast_tanh(float x){
  float e = __expf(2.0f*x);
  return 1.0f - __fdividef(2.0f, e + 1.0f);
}
__device__ __forceinline__ int detect_md(const u16* x, int* s_bad, int t, int nthr){
  if(t==0) *s_bad = 0;
  __syncthreads();
  int f=0;
  for(int i=t;i<4096;i+=nthr){ float v = bf2f(x[i]); if(!(fabsf(v)<16.0f)) f=1; }
  if(f) atomicOr(s_bad,1);
  __syncthreads();
  return *s_bad ? 0 : 1;   // 1 = bf16 inputs
}
__device__ __forceinline__ bf16x8 ld8f(const float* p){
  float4 f0 = *(const float4*)p, f1 = *(const float4*)(p+4);
  bf16x8 v;
  v[0]=(short)f2bf(f0.x); v[1]=(short)f2bf(f0.y); v[2]=(short)f2bf(f0.z); v[3]=(short)f2bf(f0.w);
  v[4]=(short)f2bf(f1.x); v[5]=(short)f2bf(f1.y); v[6]=(short)f2bf(f1.z); v[7]=(short)f2bf(f1.w);
  return v;
}
// LDS-only barrier (does not drain vmcnt).
__device__ __forceinline__ void lgkm_barrier(){
  __builtin_amdgcn_sched_barrier(0);
  asm volatile("s_waitcnt lgkmcnt(0)\n\ts_barrier" ::: "memory");
  __builtin_amdgcn_sched_barrier(0);
}

// ---------------- prepB: one kernel, 64 independent blocks -------------------
// Block (L, mt): computes P, S, Q fully in-LDS (redundant 8x — blocks are
// fully parallel on an idle machine), own R-slice, writes its share of Fsw.
// ZERO cross-block sync. All LDS buffers XOR-swizzled (conflict-free).
// Accumulation chains: (row,col) with kt ascending + same f2bf points as the
// proven 6-kernel chain -> Fsw bit-identical.
template<typename GB, typename EPI>
__device__ __forceinline__ void gfull(const u16* __restrict__ A, GB getB, EPI epi,
                                      int w, int ln, int lq){
  const int n0 = 16*w + ln;
  bf16x8 bfr[4];
  #pragma unroll
  for(int kt=0;kt<4;kt++) bfr[kt] = getB(n0, kt*32 + lq*8);
  #pragma unroll 2
  for(int rt=0; rt<8; rt++){
    f32x4 acc = {0,0,0,0};
    #pragma unroll
    for(int kt=0;kt<4;kt++){
      bf16x8 af = *(const bf16x8*)&A[SWZ8(rt*16+ln, kt*4+lq)];
      acc = MFMA16(af, bfr[kt], acc);
    }
    epi(acc, rt*16 + lq*4, n0);
  }
}

__global__ __launch_bounds__(512) void prepB(
    const void* __restrict__ xraw, const void* __restrict__ wb,
    u16* __restrict__ Fsw){
  __shared__ u16 bufA[16384];   // Wt -> S -> Qt   (swizzled)
  __shared__ u16 bufB[16384];   // P  -> Q         (swizzled)
  const int t = threadIdx.x;
  const int lane = t & 63, w = t >> 6, ln = lane & 15, lq = lane >> 4;
  const int L = blockIdx.x >> 3, mt = blockIdx.x & 7;
  const int md = detect_md((const u16*)xraw, (int*)bufA, t, 512);
  __syncthreads();   // s_bad overlays bufA: all lanes read it before Wt-conv writes
  const u16*   wbb = (const u16*)wb   + ((size_t)L<<14);
  const float* wbf = (const float*)wb + ((size_t)L<<14);

  // Wt (= f2bf(W) transposed) -> bufA. Global side vectorized (b128);
  // LDS scatter writes conflict-spread by the swizzle.
  for(int j8=t; j8<2048; j8+=512){
    int n = j8 >> 4, k0 = (j8 & 15) * 8;
    bf16x8 v = md ? *(const bf16x8*)&wbb[j8*8] : ld8f(wbf + j8*8);
    #pragma unroll
    for(int m=0;m<8;m++) bufA[SWZE(k0+m, n)] = (u16)v[m];
  }
  __syncthreads();

  auto gA = [&](int n,int k0)->bf16x8{ return *(const bf16x8*)&bufA[SWZ8(n, k0>>3)]; };
  auto gB = [&](int n,int k0)->bf16x8{ return *(const bf16x8*)&bufB[SWZ8(n, k0>>3)]; };
  auto gW = [&](int n,int k0)->bf16x8{
    if(md) return *(const bf16x8*)&wbb[n*U+k0];
    return ld8f(wbf + n*U + k0);
  };

  // P = AFACT * Wt @ Wt^T  -> bufB (full)
  gfull(bufA, gA, [&](f32x4 acc, int rowb, int n0){
    #pragma unroll
    for(int r=0;r<4;r++) bufB[SWZE(rowb+r, n0)] = f2bf(AFACT*acc[r]);
  }, w, ln, lq);
  __syncthreads();
  // S = INVC*(I - P + P@P)  -> bufA (full; Wt dead)
  gfull(bufB, gB, [&](f32x4 acc, int rowb, int n0){
    #pragma unroll
    for(int r=0;r<4;r++){
      int row = rowb + r;
      bufA[SWZE(row, n0)] = f2bf(INVC*(((row==n0)?1.0f:0.0f) - bf2f(bufB[SWZE(row, n0)]) + acc[r]));
    }
  }, w, ln, lq);
  __syncthreads();
  // Q = DT * S @ W^T  -> bufB (full; P dead). B from raw global W (== Wg bits).
  gfull(bufA, gW, [&](f32x4 acc, int rowb, int n0){
    #pragma unroll
    for(int r=0;r<4;r++) bufB[SWZE(rowb+r, n0)] = f2bf(DTc*acc[r]);
  }, w, ln, lq);
  __syncthreads();

  // swiz pass 1: this block's frag slice, quadrants F00 (S=bufA) / F01 (Q=bufB)
  for(int i = mt*1024 + t; i < (mt+1)*1024; i += 512){
    int wf = (i>>11)&3;
    if(wf >= 2) continue;
    int lanei = i & 63, kt = (i>>6)&7, c = (i>>9)&3;
    int row_n = 64*wf + 16*c + (lanei & 15);
    int c8 = kt*4 + (lanei >> 4);
    bf16x8 v = (kt < 4) ? *(const bf16x8*)&bufA[SWZ8(row_n, c8)]
                        : *(const bf16x8*)&bufB[SWZ8(row_n, c8-16)];
    *(bf16x8*)&Fsw[((size_t)L*8192 + i)*8] = v;
  }
  __syncthreads();
  // Qt = Q^T -> bufA (S dead). b128 row-reads, swizzle-spread scatter writes.
  for(int j8=t; j8<2048; j8+=512){
    int row = j8 >> 4, c0 = (j8 & 15) * 8;
    bf16x8 v = *(const bf16x8*)&bufB[SWZ8(row, c0>>3)];
    #pragma unroll
    for(int m=0;m<8;m++) bufA[SWZE(c0+m, row)] = (u16)v[m];
  }
  __syncthreads();
  // swiz pass 2: quadrant F10 (= Q^T = bufA)
  for(int i = mt*1024 + t; i < (mt+1)*1024; i += 512){
    int wf = (i>>11)&3, kt = (i>>6)&7;
    if(wf < 2 || kt >= 4) continue;
    int lanei = i & 63, c = (i>>9)&3;
    int row_n = 64*wf + 16*c + (lanei & 15);
    int c8 = kt*4 + (lanei >> 4);
    *(bf16x8*)&Fsw[((size_t)L*8192 + i)*8] = *(const bf16x8*)&bufA[SWZ8(row_n-128, c8)];
  }
  // R-slice (rows mt*16..+16): A = raw W slice (global), B = Qt rows (bufA).
  // Epilogue scatters F11 elements straight to fragment-major Fsw.
  {
    const int n0 = 16*w + ln;
    bf16x8 bq[4];
    #pragma unroll
    for(int kt=0;kt<4;kt++) bq[kt] = *(const bf16x8*)&bufA[SWZ8(n0, kt*4+lq)];
    f32x4 acc = {0,0,0,0};
    #pragma unroll
    for(int kt=0;kt<4;kt++){
      bf16x8 af = gW(mt*16 + ln, kt*32 + lq*8);
      acc = MFMA16(af, bq[kt], acc);
    }
    const int wf = 2 + (mt>>2), cc = mt & 3;
    const int kt_ = 4 + (n0>>5), lqi = (n0>>3)&3, jj = n0 & 7;
    #pragma unroll
    for(int r=0;r<4;r++){
      int lni = lq*4 + r;
      int i = (wf<<11)|(cc<<9)|(kt_<<6)|(lqi<<4)|lni;
      Fsw[((size_t)L*8192 + i)*8 + jj] = f2bf(DTc*acc[r]);
    }
  }
}

// ---------------- main: 16 rows/block, 16 waves (4/SIMD), 1 barrier/step -----
// BYTE-IDENTICAL to R5/R7's measured 125.6-126 us kernel.
__global__ __launch_bounds__(1024,4) void mainK(
    const void* __restrict__ xraw, const void* __restrict__ w_in,
    const void* __restrict__ b_in, const void* __restrict__ bb,
    const bf16x8* __restrict__ Fsw, const void* __restrict__ w_out,
    const void* __restrict__ b_out, void* __restrict__ outraw){
  __shared__ u16 At[2][16*AST];          // ping-pong A tiles [T | r_u]
  __shared__ u16 zh16[NL][16][132];      // stride 66 dwords -> u16 ops conflict-free
  __shared__ float zinu[16*U];
  __shared__ float bbL[NL*U];
  __shared__ float lg[16*12];
  __shared__ int s_bad;
  float* uout = (float*)&At[0][0];

  const int t = threadIdx.x;
  const int lane = t & 63, wid = t >> 6, ln = lane & 15, lq = lane >> 4;
  const int r0 = blockIdx.x * 16;

  const int md = detect_md((const u16*)xraw, &s_bad, t, 1024);
  for(int i=t;i<NL*U;i+=1024)
    bbL[i] = DTc * (md ? bf2f(((const u16*)bb)[i]) : ((const float*)bb)[i]);
  __syncthreads();

  // ---- phase 1: z1 = x @ w_in^T + b_in (waves 0..7 only; cols 0..127) ----
  if(wid < 8){
    const int n0 = 16*wid + ln;
    const u16*   wrb = (const u16*)w_in   + (size_t)n0*784;
    const float* wrf = (const float*)w_in + (size_t)n0*784;
    const u16*   xrb = (const u16*)xraw   + (size_t)(r0+ln)*784;
    const float* xrf = (const float*)xraw + (size_t)(r0+ln)*784;
    f32x4 acc = {0,0,0,0};
    const bf16x8 z8 = {0,0,0,0,0,0,0,0};
    if(md){
      #pragma unroll
      for(int kt=0; kt<24; ++kt){
        int k0 = kt*32 + lq*8;
        acc = MFMA16(*(const bf16x8*)(xrb + k0), *(const bf16x8*)(wrb + k0), acc);
      }
      { int k0 = 768 + lq*8;
        bf16x8 av = z8, bv = z8;
        if(lq < 2){ av = *(const bf16x8*)(xrb + k0); bv = *(const bf16x8*)(wrb + k0); }
        acc = MFMA16(av, bv, acc);
      }
    } else {
      #pragma unroll 4
      for(int kt=0; kt<24; ++kt){
        int k0 = kt*32 + lq*8;
        acc = MFMA16(ld8f(xrf + k0), ld8f(wrf + k0), acc);
      }
      { int k0 = 768 + lq*8;
        bf16x8 av = z8, bv = z8;
        if(lq < 2){ av = ld8f(xrf + k0); bv = ld8f(wrf + k0); }
        acc = MFMA16(av, bv, acc);
      }
    }
    float bi = md ? bf2f(((const u16*)b_in)[n0]) : ((const float*)b_in)[n0];
    #pragma unroll
    for(int r=0;r<4;r++) zinu[(lq*4+r)*U + n0] = acc[r] + bi;
  }
  __syncthreads();

  // ---- init: z-history (u16, unpacked), A-tile(0), r_u regs ----
  for(int i=t; i<NL*16*128; i+=1024){
    int l = i>>11, row = (i>>7)&15, c = i & 127;
    zh16[l][row][c] = f2bf(zinu[row*U + c]);
  }
  float ru[4];
  if(wid < 8){
    const int n = 16*wid + ln;
    #pragma unroll
    for(int r=0;r<4;r++){
      int row = lq*4 + r;
      At[0][row*AST + n] = f2bf((TENf + 1.0f) * fast_tanh(zinu[row*U + n]));
    }
  } else {
    const int uc = 16*(wid-8) + ln;
    #pragma unroll
    for(int r=0;r<4;r++){
      int row = lq*4 + r;
      float v = zinu[row*U + uc] + bbL[uc];
      ru[r] = v;
      At[0][row*AST + 128 + uc] = f2bf(v);
    }
  }
  // F fragment base for this wave (coalesced fragment-major)
  const bf16x8* fbase = Fsw + (wid>>2)*2048 + (wid&3)*512 + lane;
  bf16x8 BfA[8], BfB[8];
  #pragma unroll
  for(int kt=0;kt<8;kt++) BfA[kt] = fbase[kt*64];
  __syncthreads();

#define STEPBODY(STEPV, BC, BN, CURC) { \
    const int l = (STEPV) & 7; \
    const int lnext = (l+1) & 7; \
    const bool last = ((STEPV) == NS*NL-1); \
    { const bf16x8* fp = fbase + lnext*8192; \
      _Pragma("unroll") \
      for(int kt=0;kt<8;kt++) BN[kt] = fp[kt*64]; } \
    bf16x8 at8[8]; \
    _Pragma("unroll") \
    for(int kt=0;kt<8;kt++) at8[kt] = *(const bf16x8*)&At[CURC][ln*AST + kt*32 + lq*8]; \
    float th[4]; \
    if(wid < 8 && !last){ \
      _Pragma("unroll") \
      for(int r=0;r<4;r++) th[r] = TENf * fast_tanh(bf2f(zh16[lnext][lq*4 + r][16*wid + ln])); \
    } \
    f32x4 acc = {0,0,0,0}; \
    _Pragma("unroll") \
    for(int kt=0;kt<8;kt++) acc = MFMA16(at8[kt], BC[kt], acc); \
    if(wid < 8){ \
      if(!last){ \
        const bool wrap = (l == 7); \
        const int n = 16*wid + ln; \
        _Pragma("unroll") \
        for(int r=0;r<4;r++){ \
          int row = lq*4 + r; \
          float base = wrap ? fast_tanh(zinu[row*U + n]) : acc[r]; \
          At[1-(CURC)][row*AST + n] = f2bf(th[r] + base); \
        } \
      } \
    } else { \
      const int uc0 = 16*(wid-8) + ln; \
      _Pragma("unroll") \
      for(int r=0;r<4;r++){ \
        int row = lq*4 + r; \
        float yu = ru[r] - acc[r]; \
        zh16[l][row][uc0] = f2bf(yu); \
        if(last){ \
          uout[row*U + uc0] = zinu[row*U + uc0] + bbL[7*U + uc0] - acc[r]; \
        } else if(l == 7){ \
          float rn = zinu[row*U + uc0] + bbL[uc0]; \
          ru[r] = rn; \
          At[1-(CURC)][row*AST + 128 + uc0] = f2bf(rn); \
        } else { \
          float rn = yu + bbL[(l+1)*U + uc0]; \
          ru[r] = rn; \
          At[1-(CURC)][row*AST + 128 + uc0] = f2bf(rn); \
        } \
      } \
    } \
    lgkm_barrier(); \
  }

  for(int sp=0; sp<NS*NL; sp+=2){
    STEPBODY(sp,   BfA, BfB, 0)
    STEPBODY(sp+1, BfB, BfA, 1)
  }
#undef STEPBODY

  // ---- logits + softmax (w_out/b_out read directly, dual-mode) ----
  if(t < 160){
    int mm = t/10, o = t - mm*10;
    float a = md ? bf2f(((const u16*)b_out)[o]) : ((const float*)b_out)[o];
    if(md){
      const u16* wo = (const u16*)w_out + o*U;
      for(int k=0;k<U;k++) a += uout[mm*U + k]*bf2f(wo[k]);
    } else {
      const float* wo = (const float*)w_out + o*U;
      for(int k=0;k<U;k++) a += uout[mm*U + k]*wo[k];
    }
    lg[mm*12 + o] = a;
  }
  __syncthreads();
  if(t < 16){
    float mx = -1e30f;
    for(int o=0;o<10;o++) mx = fmaxf(mx, lg[t*12 + o]);
    float e[10]; float sum = 0.0f;
    for(int o=0;o<10;o++){ e[o] = __expf(lg[t*12 + o] - mx); sum += e[o]; }
    float inv = 1.0f / sum;
    for(int o=0;o<10;o++){
      float pv = e[o]*inv;
      if(md) ((u16*)outraw)[(size_t)(r0 + t)*10 + o] = f2bf(pv);
      else   ((float*)outraw)[(size_t)(r0 + t)*10 + o] = pv;
    }
  }
}

extern "C" void kernel_launch(void* const* d_in, const int* in_sizes, int n_in,
                              void* d_out, int out_size, void* d_ws, size_t ws_size,
                              hipStream_t stream) {
  u16* Fsw = (u16*)d_ws;   // 8 layers x 256x256 bf16 fragment-major = 1 MB

  prepB<<<64, 512, 0, stream>>>(d_in[0], d_in[3], Fsw);
  mainK<<<BATCH/16, 1024, 0, stream>>>(d_in[0], d_in[1], d_in[2], d_in[4],
                                       (const bf16x8*)Fsw, d_in[5], d_in[6], d_out);
}

// Round 10
// 187.577 us; speedup vs baseline: 3.6111x; 1.0768x over previous
//
#include <hip/hip_runtime.h>

#define U 128
#define BATCH 2048
#define NL 8
#define NS 8                       /* NS=15 vs 10 bit-identical -> contraction <=0.36; NS=8 residual <1e-3 */
#define DTc 0.1f
#define TENf 10.0f                 /* DT/EPS */
#define INVC (1.0f/11.0f)          /* 1/(1+DT/EPS) */
#define AFACT (0.01f/11.0f)        /* DT^2 / c */
#define AST 264                    /* A-tile LDS stride (u16); 132 dwords -> b128 reads conflict-free */
#define HST 136                    /* H-tile stride (u16); 17 dwords -> b128 reads conflict-free */

typedef unsigned short u16;
typedef unsigned int u32;
typedef __attribute__((ext_vector_type(8))) short bf16x8;
typedef __attribute__((ext_vector_type(4))) float f32x4;
#define MFMA16(a,b,c) __builtin_amdgcn_mfma_f32_16x16x32_bf16(a,b,c,0,0,0)

/* XOR-swizzled u16 index into a 128x128 LDS tile (prep only) */
#define SWZ8(row, c8)  (((row)<<7) + ((((c8) ^ ((row)&7)))<<3))
#define SWZE(row, col) (SWZ8(row, (col)>>3) + ((col)&7))

__device__ __forceinline__ float bf2f(u16 h){ return __uint_as_float(((u32)h)<<16); }
__device__ __forceinline__ u16 f2bf(float f){
  u32 u = __float_as_uint(f);
  u += 0x7FFFu + ((u >> 16) & 1u);
  return (u16)(u >> 16);
}
__device__ __forceinline__ float fast_tanh(float x){
  float e = __expf(2.0f*x);
  return 1.0f - __fdividef(2.0f, e + 1.0f);
}
__device__ __forceinline__ int detect_md(const u16* x, int* s_bad, int t, int nthr){
  if(t==0) *s_bad = 0;
  __syncthreads();
  int f=0;
  for(int i=t;i<4096;i+=nthr){ float v = bf2f(x[i]); if(!(fabsf(v)<16.0f)) f=1; }
  if(f) atomicOr(s_bad,1);
  __syncthreads();
  return *s_bad ? 0 : 1;   // 1 = bf16 inputs
}
__device__ __forceinline__ bf16x8 ld8f(const float* p){
  float4 f0 = *(const float4*)p, f1 = *(const float4*)(p+4);
  bf16x8 v;
  v[0]=(short)f2bf(f0.x); v[1]=(short)f2bf(f0.y); v[2]=(short)f2bf(f0.z); v[3]=(short)f2bf(f0.w);
  v[4]=(short)f2bf(f1.x); v[5]=(short)f2bf(f1.y); v[6]=(short)f2bf(f1.z); v[7]=(short)f2bf(f1.w);
  return v;
}
// LDS-only barrier (does not drain vmcnt -> global prefetch rides across).
__device__ __forceinline__ void lgkm_barrier(){
  __builtin_amdgcn_sched_barrier(0);
  asm volatile("s_waitcnt lgkmcnt(0)\n\ts_barrier" ::: "memory");
  __builtin_amdgcn_sched_barrier(0);
}

// ---------------- prepB: one kernel, 64 independent blocks -------------------
// Block (L, mt): computes P, S, Q fully in-LDS (redundant 8x), writes its
// share of the LEFT F fragments (F00=S rows, F01=Q rows) + its share of the
// W-row fragment stream. ZERO cross-block sync. XOR-swizzled LDS.
template<typename GB, typename EPI>
__device__ __forceinline__ void gfull(const u16* __restrict__ A, GB getB, EPI epi,
                                      int w, int ln, int lq){
  const int n0 = 16*w + ln;
  bf16x8 bfr[4];
  #pragma unroll
  for(int kt=0;kt<4;kt++) bfr[kt] = getB(n0, kt*32 + lq*8);
  #pragma unroll 2
  for(int rt=0; rt<8; rt++){
    f32x4 acc = {0,0,0,0};
    #pragma unroll
    for(int kt=0;kt<4;kt++){
      bf16x8 af = *(const bf16x8*)&A[SWZ8(rt*16+ln, kt*4+lq)];
      acc = MFMA16(af, bfr[kt], acc);
    }
    epi(acc, rt*16 + lq*4, n0);
  }
}

__global__ __launch_bounds__(512) void prepB(
    const void* __restrict__ xraw, const void* __restrict__ wb,
    u16* __restrict__ Fsw, u16* __restrict__ Wfr){
  __shared__ u16 bufA[16384];   // Wt -> S   (swizzled)
  __shared__ u16 bufB[16384];   // P  -> Q   (swizzled)
  const int t = threadIdx.x;
  const int lane = t & 63, w = t >> 6, ln = lane & 15, lq = lane >> 4;
  const int L = blockIdx.x >> 3, mt = blockIdx.x & 7;
  const int md = detect_md((const u16*)xraw, (int*)bufA, t, 512);
  __syncthreads();   // s_bad overlays bufA
  const u16*   wbb = (const u16*)wb   + ((size_t)L<<14);
  const float* wbf = (const float*)wb + ((size_t)L<<14);

  // W-row fragment gather: block mt writes wave-mt's frags for layer L.
  // Wfr[L][w][kt][lane] = W[16w+lni][32kt+8lqi .. +7]
  if(t < 256){
    int kt = t >> 6, lanei = t & 63, lni = lanei & 15, lqi = lanei >> 4;
    bf16x8 v = md ? *(const bf16x8*)&wbb[(16*mt+lni)*U + 32*kt + 8*lqi]
                  : ld8f(wbf + (16*mt+lni)*U + 32*kt + 8*lqi);
    *(bf16x8*)&Wfr[((size_t)L*2048 + mt*256 + t)*8] = v;
  }

  // Wt (= f2bf(W) transposed) -> bufA
  for(int j8=t; j8<2048; j8+=512){
    int n = j8 >> 4, k0 = (j8 & 15) * 8;
    bf16x8 v = md ? *(const bf16x8*)&wbb[j8*8] : ld8f(wbf + j8*8);
    #pragma unroll
    for(int m=0;m<8;m++) bufA[SWZE(k0+m, n)] = (u16)v[m];
  }
  __syncthreads();

  auto gA = [&](int n,int k0)->bf16x8{ return *(const bf16x8*)&bufA[SWZ8(n, k0>>3)]; };
  auto gB = [&](int n,int k0)->bf16x8{ return *(const bf16x8*)&bufB[SWZ8(n, k0>>3)]; };
  auto gW = [&](int n,int k0)->bf16x8{
    if(md) return *(const bf16x8*)&wbb[n*U+k0];
    return ld8f(wbf + n*U + k0);
  };

  // P = AFACT * Wt @ Wt^T  -> bufB
  gfull(bufA, gA, [&](f32x4 acc, int rowb, int n0){
    #pragma unroll
    for(int r=0;r<4;r++) bufB[SWZE(rowb+r, n0)] = f2bf(AFACT*acc[r]);
  }, w, ln, lq);
  __syncthreads();
  // S = INVC*(I - P + P@P)  -> bufA
  gfull(bufB, gB, [&](f32x4 acc, int rowb, int n0){
    #pragma unroll
    for(int r=0;r<4;r++){
      int row = rowb + r;
      bufA[SWZE(row, n0)] = f2bf(INVC*(((row==n0)?1.0f:0.0f) - bf2f(bufB[SWZE(row, n0)]) + acc[r]));
    }
  }, w, ln, lq);
  __syncthreads();
  // Q = DT * S @ W^T  -> bufB
  gfull(bufA, gW, [&](f32x4 acc, int rowb, int n0){
    #pragma unroll
    for(int r=0;r<4;r++) bufB[SWZE(rowb+r, n0)] = f2bf(DTc*acc[r]);
  }, w, ln, lq);
  __syncthreads();

  // swizzle LEFT F frags: quadrants F00 (S=bufA, kt 0-3) / F01 (Q=bufB, kt 4-7)
  for(int i = mt*1024 + t; i < (mt+1)*1024; i += 512){
    int wf = (i>>11)&3;
    if(wf >= 2) continue;
    int lanei = i & 63, kt = (i>>6)&7, c = (i>>9)&3;
    int row_n = 64*wf + 16*c + (lanei & 15);
    int c8 = kt*4 + (lanei >> 4);
    bf16x8 v = (kt < 4) ? *(const bf16x8*)&bufA[SWZ8(row_n, c8)]
                        : *(const bf16x8*)&bufB[SWZ8(row_n, c8-16)];
    *(bf16x8*)&Fsw[((size_t)L*8192 + i)*8] = v;
  }
}

// ---------------- mainG: 16 rows/block, 8 dual-role waves, 96 KB/step --------
// Factored step: accL = [T|r]@[S;Q] (BITWISE identical to previous left half);
// H = f2bf(accL) via 4 KB LDS roundtrip; accR = H @ W-rows, right = DT*accR
// (exact-math identical to T@Q + r@R; rounding realigned). Wave w owns column
// group 16w+ln for BOTH roles -> zinu/bb/zh all lane-local.
__global__ __launch_bounds__(512,2) void mainG(
    const void* __restrict__ xraw, const void* __restrict__ w_in,
    const void* __restrict__ b_in, const void* __restrict__ bb,
    const bf16x8* __restrict__ Fsw, const bf16x8* __restrict__ Wfr,
    const void* __restrict__ w_out, const void* __restrict__ b_out,
    void* __restrict__ outraw){
  __shared__ u16 At[2][16*AST];          // ping-pong A tiles [T | r_u]
  __shared__ u16 zh16[NL][16][132];      // lane-local y_u history (bf16)
  __shared__ u16 Hld[16*HST];            // H roundtrip (bf16)
  __shared__ float lg[16*12];
  __shared__ int s_bad;
  float* uout = (float*)&At[0][0];

  const int t = threadIdx.x;
  const int lane = t & 63, w = t >> 6, ln = lane & 15, lq = lane >> 4;
  const int r0 = blockIdx.x * 16;
  const int n = 16*w + ln;               // this lane's column (T and u roles)

  const int md = detect_md((const u16*)xraw, &s_bad, t, 512);
  float bbLr[NL];
  #pragma unroll
  for(int l=0;l<NL;l++)
    bbLr[l] = DTc * (md ? bf2f(((const u16*)bb)[l*U+n]) : ((const float*)bb)[l*U+n]);

  // ---- phase 1: z1 = x @ w_in^T + b_in -> zr[4] (registers) ----
  float zr[4];
  {
    const u16*   wrb = (const u16*)w_in   + (size_t)n*784;
    const float* wrf = (const float*)w_in + (size_t)n*784;
    const u16*   xrb = (const u16*)xraw   + (size_t)(r0+ln)*784;
    const float* xrf = (const float*)xraw + (size_t)(r0+ln)*784;
    f32x4 acc = {0,0,0,0};
    const bf16x8 z8 = {0,0,0,0,0,0,0,0};
    if(md){
      #pragma unroll
      for(int kt=0; kt<24; ++kt){
        int k0 = kt*32 + lq*8;
        acc = MFMA16(*(const bf16x8*)(xrb + k0), *(const bf16x8*)(wrb + k0), acc);
      }
      { int k0 = 768 + lq*8;
        bf16x8 av = z8, bv = z8;
        if(lq < 2){ av = *(const bf16x8*)(xrb + k0); bv = *(const bf16x8*)(wrb + k0); }
        acc = MFMA16(av, bv, acc);
      }
    } else {
      #pragma unroll 4
      for(int kt=0; kt<24; ++kt){
        int k0 = kt*32 + lq*8;
        acc = MFMA16(ld8f(xrf + k0), ld8f(wrf + k0), acc);
      }
      { int k0 = 768 + lq*8;
        bf16x8 av = z8, bv = z8;
        if(lq < 2){ av = ld8f(xrf + k0); bv = ld8f(wrf + k0); }
        acc = MFMA16(av, bv, acc);
      }
    }
    float bi = md ? bf2f(((const u16*)b_in)[n]) : ((const float*)b_in)[n];
    #pragma unroll
    for(int r=0;r<4;r++) zr[r] = acc[r] + bi;
  }

  // ---- init: zh history, At(0), ru regs (all from local zr) ----
  #pragma unroll
  for(int l=0;l<NL;l++){
    #pragma unroll
    for(int r=0;r<4;r++) zh16[l][lq*4+r][n] = f2bf(zr[r]);
  }
  float ru[4];
  #pragma unroll
  for(int r=0;r<4;r++){
    int row = lq*4 + r;
    At[0][row*AST + n] = f2bf((TENf + 1.0f) * fast_tanh(zr[r]));
    float v = zr[r] + bbLr[0];
    ru[r] = v;
    At[0][row*AST + 128 + n] = f2bf(v);
  }
  const bf16x8* fbase = Fsw + (w>>2)*2048 + (w&3)*512 + lane;  // left F frags
  const bf16x8* wfb   = Wfr + w*256 + lane;                    // W-row frags
  bf16x8 BfA[8], BfB[8], WfA[4], WfB[4];
  #pragma unroll
  for(int kt=0;kt<8;kt++) BfA[kt] = fbase[kt*64];
  #pragma unroll
  for(int kt=0;kt<4;kt++) WfA[kt] = wfb[kt*64];
  __syncthreads();

#define STEPBODY(STEPV, BC, BN, WC, WN, CURC) { \
    const int l = (STEPV) & 7; \
    const int lnext = (l+1) & 7; \
    const bool last = ((STEPV) == NS*NL-1); \
    const bool wrap = (l == 7); \
    { const bf16x8* fp = fbase + lnext*8192; \
      _Pragma("unroll") \
      for(int kt=0;kt<8;kt++) BN[kt] = fp[kt*64]; \
      const bf16x8* wp = wfb + lnext*2048; \
      _Pragma("unroll") \
      for(int kt=0;kt<4;kt++) WN[kt] = wp[kt*64]; } \
    bf16x8 at8[8]; \
    _Pragma("unroll") \
    for(int kt=0;kt<8;kt++) at8[kt] = *(const bf16x8*)&At[CURC][ln*AST + kt*32 + lq*8]; \
    float th[4]; \
    if(!last){ \
      _Pragma("unroll") \
      for(int r=0;r<4;r++) th[r] = TENf * fast_tanh(bf2f(zh16[lnext][lq*4 + r][n])); \
    } \
    f32x4 accL = {0,0,0,0}; \
    _Pragma("unroll") \
    for(int kt=0;kt<8;kt++) accL = MFMA16(at8[kt], BC[kt], accL); \
    _Pragma("unroll") \
    for(int r=0;r<4;r++) Hld[(lq*4+r)*HST + n] = f2bf(accL[r]); \
    lgkm_barrier(); \
    bf16x8 hf[4]; \
    _Pragma("unroll") \
    for(int kt=0;kt<4;kt++) hf[kt] = *(const bf16x8*)&Hld[ln*HST + kt*32 + lq*8]; \
    f32x4 accR = {0,0,0,0}; \
    _Pragma("unroll") \
    for(int kt=0;kt<4;kt++) accR = MFMA16(hf[kt], WC[kt], accR); \
    if(!last){ \
      _Pragma("unroll") \
      for(int r=0;r<4;r++){ \
        int row = lq*4 + r; \
        float base = wrap ? fast_tanh(zr[r]) : accL[r]; \
        At[1-(CURC)][row*AST + n] = f2bf(th[r] + base); \
      } \
      _Pragma("unroll") \
      for(int r=0;r<4;r++){ \
        int row = lq*4 + r; \
        float yu = ru[r] - DTc*accR[r]; \
        zh16[l][row][n] = f2bf(yu); \
        float rn = wrap ? (zr[r] + bbLr[0]) : (yu + bbLr[(l+1)&7]); \
        ru[r] = rn; \
        At[1-(CURC)][row*AST + 128 + n] = f2bf(rn); \
      } \
    } else { \
      _Pragma("unroll") \
      for(int r=0;r<4;r++){ \
        int row = lq*4 + r; \
        uout[row*U + n] = zr[r] + bbLr[7] - DTc*accR[r]; \
      } \
    } \
    lgkm_barrier(); \
  }

  for(int sp=0; sp<NS*NL; sp+=2){
    STEPBODY(sp,   BfA, BfB, WfA, WfB, 0)
    STEPBODY(sp+1, BfB, BfA, WfB, WfA, 1)
  }
#undef STEPBODY

  // ---- logits + softmax ----
  if(t < 160){
    int mm = t/10, o = t - mm*10;
    float a = md ? bf2f(((const u16*)b_out)[o]) : ((const float*)b_out)[o];
    if(md){
      const u16* wo = (const u16*)w_out + o*U;
      for(int k=0;k<U;k++) a += uout[mm*U + k]*bf2f(wo[k]);
    } else {
      const float* wo = (const float*)w_out + o*U;
      for(int k=0;k<U;k++) a += uout[mm*U + k]*wo[k];
    }
    lg[mm*12 + o] = a;
  }
  __syncthreads();
  if(t < 16){
    float mx = -1e30f;
    for(int o=0;o<10;o++) mx = fmaxf(mx, lg[t*12 + o]);
    float e[10]; float sum = 0.0f;
    for(int o=0;o<10;o++){ e[o] = __expf(lg[t*12 + o] - mx); sum += e[o]; }
    float inv = 1.0f / sum;
    for(int o=0;o<10;o++){
      float pv = e[o]*inv;
      if(md) ((u16*)outraw)[(size_t)(r0 + t)*10 + o] = f2bf(pv);
      else   ((float*)outraw)[(size_t)(r0 + t)*10 + o] = pv;
    }
  }
}

extern "C" void kernel_launch(void* const* d_in, const int* in_sizes, int n_in,
                              void* d_out, int out_size, void* d_ws, size_t ws_size,
                              hipStream_t stream) {
  char* p = (char*)d_ws;
  u16* Fsw = (u16*)p;  p += (size_t)8*256*256*2;   // 1 MB (left half used)
  u16* Wfr = (u16*)p;  p += (size_t)8*128*128*2;   // 256 KB W-row frags

  prepB<<<64, 512, 0, stream>>>(d_in[0], d_in[3], Fsw, Wfr);
  mainG<<<BATCH/16, 512, 0, stream>>>(d_in[0], d_in[1], d_in[2], d_in[4],
                                      (const bf16x8*)Fsw, (const bf16x8*)Wfr,
                                      d_in[5], d_in[6], d_out);
}